// Round 9
// baseline (3077.004 us; speedup 1.0000x reference)
//
#include <hip/hip_runtime.h>
#include <hip/hip_bf16.h>
#include <math.h>

#define NN 50000
#define TT 12
#define FF 32
#define HH 64

static inline size_t align256(size_t x){ return (x + 255) & ~(size_t)255; }

// ---------------- graph preprocessing ----------------

__global__ void k_count(const int* __restrict__ dst, int E, int* __restrict__ cnt){
  int i = blockIdx.x*blockDim.x + threadIdx.x;
  if (i < E) atomicAdd(&cnt[dst[i]], 1);
}

__global__ void k_dinv(const int* __restrict__ cnt, float* __restrict__ dinv,
                       float* __restrict__ invd, int n){
  int i = blockIdx.x*blockDim.x + threadIdx.x;
  if (i < n){
    float d = (float)(cnt[i] + 1);            // +1 self loop
    dinv[i] = (float)(1.0 / sqrt((double)d));
    invd[i] = 1.0f / d;
  }
}

#define SCAN_T 256
__global__ void k_scan(const int* __restrict__ cnt, int* __restrict__ rp, int n){
  __shared__ int s[SCAN_T];
  int t = threadIdx.x;
  int chunk = (n + SCAN_T - 1) / SCAN_T;
  int lo = t*chunk, hi = min(lo+chunk, n);
  int sum = 0;
  for (int i = lo; i < hi; ++i) sum += cnt[i];
  s[t] = sum; __syncthreads();
  for (int off = 1; off < SCAN_T; off <<= 1){
    int v = (t >= off) ? s[t-off] : 0;
    __syncthreads();
    s[t] += v;
    __syncthreads();
  }
  int run = (t == 0) ? 0 : s[t-1];
  for (int i = lo; i < hi; ++i){ rp[i] = run; run += cnt[i]; }
  if (t == SCAN_T-1) rp[n] = run;
}

// packed edge record: .x = src index, .y = norm (float bits). ONE 8B scatter
// store per edge (was 2x 4B to two arrays -> ~2x dirty-line traffic).
__global__ void k_fill(const int* __restrict__ src, const int* __restrict__ dst, int E,
                       const int* __restrict__ rp, int* __restrict__ cur,
                       const float* __restrict__ dinv,
                       int2* __restrict__ ef){
  int i = blockIdx.x*blockDim.x + threadIdx.x;
  if (i < E){
    int d = dst[i], s = src[i];
    int pos = rp[d] + atomicAdd(&cur[d], 1);
    int2 rec; rec.x = s; rec.y = __float_as_int(dinv[s] * dinv[d]);
    ef[pos] = rec;
  }
}

// ---------------- fused layer 1: h1 = relu( (A x_t) W1 + b1 ) ---------------
// Wave per node. Aggregation: half-waves split even/odd edges (lane&31 = f).
// Fold halves + mini-GEMM via per-wave LDS (wave-synchronous, lockstep-64).
// GEMM: lane = output col j, W1 column (32 floats) in VGPRs.
__launch_bounds__(256)
__global__ void k_l1(const float* __restrict__ xt, const int* __restrict__ rp,
                     const int2* __restrict__ ef, const float* __restrict__ invd,
                     const float* __restrict__ W1, const float* __restrict__ b1,
                     float* __restrict__ h1){
  __shared__ float sh[4][2][32];
  int wv = threadIdx.x >> 6, lane = threadIdx.x & 63;
  int n = blockIdx.x*4 + wv;
  if (n >= NN) return;
  float w1c[32];
  #pragma unroll
  for (int k = 0; k < 32; ++k) w1c[k] = W1[k*64 + lane];
  float bj = b1[lane];
  int half = lane >> 5, f = lane & 31;

  float acc = half ? 0.f : invd[n] * xt[(size_t)n*FF + f];
  int e = rp[n] + half, e1 = rp[n+1];
  for (; e + 2 < e1; e += 4){
    int2 p = ef[e], q = ef[e+2];
    acc = fmaf(__int_as_float(p.y), xt[(size_t)p.x*FF + f], acc);
    acc = fmaf(__int_as_float(q.y), xt[(size_t)q.x*FF + f], acc);
  }
  if (e < e1){
    int2 p = ef[e];
    acc = fmaf(__int_as_float(p.y), xt[(size_t)p.x*FF + f], acc);
  }
  sh[wv][half][f] = acc;                 // intra-wave LDS (lockstep; lgkmcnt)
  if (lane < 32) sh[wv][0][f] = acc + sh[wv][1][f];
  float hj = bj;
  const float4* row = (const float4*)&sh[wv][0][0];
  #pragma unroll
  for (int i4 = 0; i4 < 8; ++i4){
    float4 v = row[i4];                  // same-addr broadcast
    hj = fmaf(v.x, w1c[4*i4  ], hj);
    hj = fmaf(v.y, w1c[4*i4+1], hj);
    hj = fmaf(v.z, w1c[4*i4+2], hj);
    hj = fmaf(v.w, w1c[4*i4+3], hj);
  }
  h1[(size_t)n*HH + lane] = fmaxf(hj, 0.f);
}

// ---------------- fused layer 2: h2 = relu( (A h1) W2 + b2 ) ----------------
// Wave per node; lane = feature during aggregation (256B gathers), then
// lane = output col for the mini-GEMM (W2 column, 64 floats, in VGPRs).
__launch_bounds__(256)
__global__ void k_l2(const float* __restrict__ h1, const int* __restrict__ rp,
                     const int2* __restrict__ ef, const float* __restrict__ invd,
                     const float* __restrict__ W2, const float* __restrict__ b2,
                     float* __restrict__ h2){
  __shared__ float sh[4][64];
  int wv = threadIdx.x >> 6, lane = threadIdx.x & 63;
  int n = blockIdx.x*4 + wv;
  if (n >= NN) return;
  float w2c[64];
  #pragma unroll
  for (int k = 0; k < 64; ++k) w2c[k] = W2[k*64 + lane];
  float bj = b2[lane];

  float acc = invd[n] * h1[(size_t)n*HH + lane];
  int e = rp[n], e1 = rp[n+1];
  for (; e + 4 <= e1; e += 4){
    int2 p0 = ef[e], p1 = ef[e+1], p2 = ef[e+2], p3 = ef[e+3];
    float v0 = h1[(size_t)p0.x*HH + lane];
    float v1 = h1[(size_t)p1.x*HH + lane];
    float v2 = h1[(size_t)p2.x*HH + lane];
    float v3 = h1[(size_t)p3.x*HH + lane];
    acc = fmaf(__int_as_float(p0.y), v0, acc);
    acc = fmaf(__int_as_float(p1.y), v1, acc);
    acc = fmaf(__int_as_float(p2.y), v2, acc);
    acc = fmaf(__int_as_float(p3.y), v3, acc);
  }
  for (; e < e1; ++e){
    int2 p = ef[e];
    acc = fmaf(__int_as_float(p.y), h1[(size_t)p.x*HH + lane], acc);
  }
  sh[wv][lane] = acc;                    // intra-wave LDS
  float hj = bj;
  const float4* row = (const float4*)&sh[wv][0];
  #pragma unroll
  for (int i4 = 0; i4 < 16; ++i4){
    float4 v = row[i4];
    hj = fmaf(v.x, w2c[4*i4  ], hj);
    hj = fmaf(v.y, w2c[4*i4+1], hj);
    hj = fmaf(v.z, w2c[4*i4+2], hj);
    hj = fmaf(v.w, w2c[4*i4+3], hj);
  }
  h2[(size_t)n*HH + lane] = fmaxf(hj, 0.f);
}

// ---------------- fused GRU step (v3, verified) ------------------------------
#define GRB 16
__launch_bounds__(384)
__global__ void k_gruf(const float* __restrict__ h2, const float* __restrict__ hprev,
                       const float* __restrict__ Wih, const float* __restrict__ Whh,
                       const float* __restrict__ bih, const float* __restrict__ bhh,
                       float* __restrict__ hnew, int ntiles){
  __shared__ float sh[2][GRB][64];   // [0]=h2 rows, [1]=hprev rows (8 KB)
  __shared__ float ex[6][GRB][64];   // gate exchange (24 KB)
  int tid = threadIdx.x, wv = tid >> 6, lane = tid & 63;
  int side = wv / 3;
  int gate = wv - side*3;
  const float* Wsel = side ? Whh : Wih;
  float bg = (side ? bhh : bih)[gate*64 + lane];
  float w[64];
  {
    const float* wr = Wsel + (size_t)(gate*64 + lane)*64;
    #pragma unroll
    for (int k = 0; k < 64; k += 4){
      float4 v = *(const float4*)(wr + k);
      w[k]=v.x; w[k+1]=v.y; w[k+2]=v.z; w[k+3]=v.w;
    }
  }

  for (int tile = blockIdx.x; tile < ntiles; tile += gridDim.x){
    int n0 = tile * GRB;
    __syncthreads();   // sh/ex free (previous epilogue done)
    for (int i = tid; i < 2*GRB*16; i += 384){
      if (i < GRB*16) ((float4*)sh)[i] = ((const float4*)(h2    + (size_t)n0*64))[i];
      else            ((float4*)sh)[i] = ((const float4*)(hprev + (size_t)n0*64))[i - GRB*16];
    }
    __syncthreads();

    float a[GRB];
    #pragma unroll
    for (int r0 = 0; r0 < GRB; r0 += 4){
      const float* h0 = &sh[side][r0    ][0];
      const float* h1p= &sh[side][r0 + 1][0];
      const float* h2p= &sh[side][r0 + 2][0];
      const float* h3 = &sh[side][r0 + 3][0];
      float s0=0.f, s1=0.f, s2=0.f, s3=0.f;
      #pragma unroll
      for (int k = 0; k < 64; k += 4){
        float4 v0 = *(const float4*)(h0 + k);
        float4 v1 = *(const float4*)(h1p + k);
        float4 v2 = *(const float4*)(h2p + k);
        float4 v3 = *(const float4*)(h3 + k);
        s0 = fmaf(v0.x, w[k], s0); s0 = fmaf(v0.y, w[k+1], s0);
        s0 = fmaf(v0.z, w[k+2], s0); s0 = fmaf(v0.w, w[k+3], s0);
        s1 = fmaf(v1.x, w[k], s1); s1 = fmaf(v1.y, w[k+1], s1);
        s1 = fmaf(v1.z, w[k+2], s1); s1 = fmaf(v1.w, w[k+3], s1);
        s2 = fmaf(v2.x, w[k], s2); s2 = fmaf(v2.y, w[k+1], s2);
        s2 = fmaf(v2.z, w[k+2], s2); s2 = fmaf(v2.w, w[k+3], s2);
        s3 = fmaf(v3.x, w[k], s3); s3 = fmaf(v3.y, w[k+1], s3);
        s3 = fmaf(v3.z, w[k+2], s3); s3 = fmaf(v3.w, w[k+3], s3);
      }
      a[r0]=s0; a[r0+1]=s1; a[r0+2]=s2; a[r0+3]=s3;
    }
    #pragma unroll
    for (int r = 0; r < GRB; ++r) ex[wv][r][lane] = a[r] + bg;
    __syncthreads();
    for (int i = tid; i < GRB*64; i += 384){
      int row = i >> 6, col = i & 63;
      float ir = ex[0][row][col], iz = ex[1][row][col], in_ = ex[2][row][col];
      float hr = ex[3][row][col], hz = ex[4][row][col], hn  = ex[5][row][col];
      float rg = 1.f/(1.f + expf(-(ir + hr)));
      float zg = 1.f/(1.f + expf(-(iz + hz)));
      float nv = tanhf(in_ + rg*hn);
      float hp = sh[1][row][col];
      hnew[(size_t)(n0 + row)*64 + col] = (1.f - zg)*nv + zg*hp;
    }
  }
}

// ---------------- head: logits = relu(h@Wc1+bc1)@Wc2 + bc2 ----------------
__global__ void k_head(const float* __restrict__ h, const float* __restrict__ Wc1,
                       const float* __restrict__ bc1, const float* __restrict__ Wc2,
                       const float* __restrict__ bc2, float* __restrict__ out){
  __shared__ float w1[64*32];
  __shared__ float w2[32];
  for (int i = threadIdx.x; i < 64*32; i += blockDim.x) w1[i] = Wc1[i];
  if (threadIdx.x < 32) w2[threadIdx.x] = Wc2[threadIdx.x];
  __syncthreads();
  int n = blockIdx.x*blockDim.x + threadIdx.x;
  if (n >= NN) return;
  const float* hr = h + (size_t)n*64;
  float hreg[64];
  #pragma unroll
  for (int k = 0; k < 64; ++k) hreg[k] = hr[k];
  float acc2 = bc2[0];
  #pragma unroll
  for (int c = 0; c < 32; ++c){
    float a = bc1[c];
    #pragma unroll
    for (int k = 0; k < 64; ++k) a = fmaf(hreg[k], w1[k*32 + c], a);
    a = fmaxf(a, 0.f);
    acc2 = fmaf(a, w2[c], acc2);
  }
  out[n] = acc2;
}

// ---------------- launch ----------------
extern "C" void kernel_launch(void* const* d_in, const int* in_sizes, int n_in,
                              void* d_out, int out_size, void* d_ws, size_t ws_size,
                              hipStream_t stream){
  const float* x    = (const float*)d_in[0];
  const int*   ei   = (const int*)  d_in[1];
  const float* W1   = (const float*)d_in[2];
  const float* b1   = (const float*)d_in[3];
  const float* W2   = (const float*)d_in[4];
  const float* b2   = (const float*)d_in[5];
  const float* W_ih = (const float*)d_in[6];
  const float* W_hh = (const float*)d_in[7];
  const float* b_ih = (const float*)d_in[8];
  const float* b_hh = (const float*)d_in[9];
  const float* Wc1  = (const float*)d_in[10];
  const float* bc1  = (const float*)d_in[11];
  const float* Wc2  = (const float*)d_in[12];
  const float* bc2  = (const float*)d_in[13];
  int E = in_sizes[1] / 2;
  const int* src = ei;
  const int* dst = ei + E;

  char* w = (char*)d_ws;
  auto alloc = [&](size_t bytes){ char* p = w; w += align256(bytes); return p; };
  int*   cnt  = (int*)  alloc((size_t)NN*4);
  int*   rp   = (int*)  alloc((size_t)(NN+1)*4);
  int*   cur  = (int*)  alloc((size_t)NN*4);
  float* dinv = (float*)alloc((size_t)NN*4);
  float* invd = (float*)alloc((size_t)NN*4);
  int2*  ef   = (int2*) alloc((size_t)E*8);
  float* h1   = (float*)alloc((size_t)NN*HH*4);
  float* h2   = (float*)alloc((size_t)NN*HH*4);
  float* hA   = (float*)alloc((size_t)NN*HH*4);
  float* hB   = (float*)alloc((size_t)NN*HH*4);
  if ((size_t)(w - (char*)d_ws) > ws_size) return;   // clean diagnostic fail

  hipMemsetAsync(cnt, 0, (size_t)NN*4, stream);
  hipMemsetAsync(cur, 0, (size_t)NN*4, stream);
  hipMemsetAsync(hA,  0, (size_t)NN*HH*4, stream);   // h0 = 0

  k_count<<<(E+255)/256, 256, 0, stream>>>(dst, E, cnt);
  k_dinv <<<(NN+255)/256, 256, 0, stream>>>(cnt, dinv, invd, NN);
  k_scan <<<1, SCAN_T, 0, stream>>>(cnt, rp, NN);
  k_fill <<<(E+255)/256, 256, 0, stream>>>(src, dst, E, rp, cur, dinv, ef);

  float* hprev = hA;
  float* hnext = hB;
  for (int t = 0; t < TT; ++t){
    const float* xt = x + (size_t)t*NN*FF;
    k_l1<<<(NN + 3)/4, 256, 0, stream>>>(xt, rp, ef, invd, W1, b1, h1);
    k_l2<<<(NN + 3)/4, 256, 0, stream>>>(h1, rp, ef, invd, W2, b2, h2);
    k_gruf<<<1024, 384, 0, stream>>>(h2, hprev, W_ih, W_hh, b_ih, b_hh, hnext, NN/GRB);
    float* tmp = hprev; hprev = hnext; hnext = tmp;
  }

  // after 12 swaps hprev == hA
  k_head<<<(NN + 255)/256, 256, 0, stream>>>(hprev, Wc1, bc1, Wc2, bc2, (float*)d_out);
}

// Round 10
// 2735.122 us; speedup vs baseline: 1.1250x; 1.1250x over previous
//
#include <hip/hip_runtime.h>
#include <hip/hip_bf16.h>
#include <math.h>

#define NN 50000
#define TT 12
#define FF 32
#define HH 64

static inline size_t align256(size_t x){ return (x + 255) & ~(size_t)255; }

// ---------------- graph preprocessing ----------------

__global__ void k_count(const int* __restrict__ dst, int E, int* __restrict__ cnt){
  int i = blockIdx.x*blockDim.x + threadIdx.x;
  if (i < E) atomicAdd(&cnt[dst[i]], 1);
}

__global__ void k_dinv(const int* __restrict__ cnt, float* __restrict__ dinv,
                       float* __restrict__ invd, int n){
  int i = blockIdx.x*blockDim.x + threadIdx.x;
  if (i < n){
    float d = (float)(cnt[i] + 1);            // +1 self loop
    dinv[i] = (float)(1.0 / sqrt((double)d));
    invd[i] = 1.0f / d;
  }
}

#define SCAN_T 256
__global__ void k_scan(const int* __restrict__ cnt, int* __restrict__ rp, int n){
  __shared__ int s[SCAN_T];
  int t = threadIdx.x;
  int chunk = (n + SCAN_T - 1) / SCAN_T;
  int lo = t*chunk, hi = min(lo+chunk, n);
  int sum = 0;
  for (int i = lo; i < hi; ++i) sum += cnt[i];
  s[t] = sum; __syncthreads();
  for (int off = 1; off < SCAN_T; off <<= 1){
    int v = (t >= off) ? s[t-off] : 0;
    __syncthreads();
    s[t] += v;
    __syncthreads();
  }
  int run = (t == 0) ? 0 : s[t-1];
  for (int i = lo; i < hi; ++i){ rp[i] = run; run += cnt[i]; }
  if (t == SCAN_T-1) rp[n] = run;
}

// packed edge record: .x = src index, .y = norm (float bits). ONE 8B scatter.
__global__ void k_fill(const int* __restrict__ src, const int* __restrict__ dst, int E,
                       const int* __restrict__ rp, int* __restrict__ cur,
                       const float* __restrict__ dinv,
                       int2* __restrict__ ef){
  int i = blockIdx.x*blockDim.x + threadIdx.x;
  if (i < E){
    int d = dst[i], s = src[i];
    int pos = rp[d] + atomicAdd(&cur[d], 1);
    int2 rec; rec.x = s; rec.y = __float_as_int(dinv[s] * dinv[d]);
    ef[pos] = rec;
  }
}

// ---------------- fused layer 1: h1 = relu( (A x_t) W1 + b1 ) ---------------
// Wave per node. Half-waves split even/odd edges (f = lane&31); 4 edges per
// half per iteration -> 8 gathers in flight per wave (latency hiding).
__launch_bounds__(256)
__global__ void k_l1(const float* __restrict__ xt, const int* __restrict__ rp,
                     const int2* __restrict__ ef, const float* __restrict__ invd,
                     const float* __restrict__ W1, const float* __restrict__ b1,
                     float* __restrict__ h1){
  __shared__ float sh[4][2][32];
  int wv = threadIdx.x >> 6, lane = threadIdx.x & 63;
  int n = blockIdx.x*4 + wv;
  if (n >= NN) return;
  int half = lane >> 5, f = lane & 31;

  float acc0 = half ? 0.f : invd[n] * xt[(size_t)n*FF + f];
  float acc1 = 0.f;
  int e = rp[n] + half, e1 = rp[n+1];
  for (; e + 6 < e1; e += 8){                 // 4 edges per half per iter
    int2 p0 = ef[e], p1 = ef[e+2], p2 = ef[e+4], p3 = ef[e+6];
    float v0 = xt[(size_t)p0.x*FF + f];
    float v1 = xt[(size_t)p1.x*FF + f];
    float v2 = xt[(size_t)p2.x*FF + f];
    float v3 = xt[(size_t)p3.x*FF + f];
    acc0 = fmaf(__int_as_float(p0.y), v0, acc0);
    acc1 = fmaf(__int_as_float(p1.y), v1, acc1);
    acc0 = fmaf(__int_as_float(p2.y), v2, acc0);
    acc1 = fmaf(__int_as_float(p3.y), v3, acc1);
  }
  for (; e < e1; e += 2){
    int2 p = ef[e];
    acc0 = fmaf(__int_as_float(p.y), xt[(size_t)p.x*FF + f], acc0);
  }
  float acc = acc0 + acc1;
  sh[wv][half][f] = acc;                 // intra-wave LDS (lockstep)
  if (lane < 32) sh[wv][0][f] = acc + sh[wv][1][f];
  float hj = b1[lane];
  const float4* row = (const float4*)&sh[wv][0][0];
  #pragma unroll
  for (int i4 = 0; i4 < 8; ++i4){
    float4 v = row[i4];                  // same-addr broadcast
    hj = fmaf(v.x, W1[(4*i4  )*HH + lane], hj);
    hj = fmaf(v.y, W1[(4*i4+1)*HH + lane], hj);
    hj = fmaf(v.z, W1[(4*i4+2)*HH + lane], hj);
    hj = fmaf(v.w, W1[(4*i4+3)*HH + lane], hj);
  }
  h1[(size_t)n*HH + lane] = fmaxf(hj, 0.f);
}

// ---------------- fused layer 2: h2 = relu( (A h1) W2 + b2 ) ----------------
// Wave per node; lane = feature; 8 edges unrolled -> 8 gathers in flight.
__launch_bounds__(256)
__global__ void k_l2(const float* __restrict__ h1, const int* __restrict__ rp,
                     const int2* __restrict__ ef, const float* __restrict__ invd,
                     const float* __restrict__ W2, const float* __restrict__ b2,
                     float* __restrict__ h2){
  __shared__ float sh[4][64];
  int wv = threadIdx.x >> 6, lane = threadIdx.x & 63;
  int n = blockIdx.x*4 + wv;
  if (n >= NN) return;

  float acc0 = invd[n] * h1[(size_t)n*HH + lane];
  float acc1 = 0.f;
  int e = rp[n], e1 = rp[n+1];
  for (; e + 8 <= e1; e += 8){
    int2 p0 = ef[e  ], p1 = ef[e+1], p2 = ef[e+2], p3 = ef[e+3];
    int2 p4 = ef[e+4], p5 = ef[e+5], p6 = ef[e+6], p7 = ef[e+7];
    float v0 = h1[(size_t)p0.x*HH + lane];
    float v1 = h1[(size_t)p1.x*HH + lane];
    float v2 = h1[(size_t)p2.x*HH + lane];
    float v3 = h1[(size_t)p3.x*HH + lane];
    float v4 = h1[(size_t)p4.x*HH + lane];
    float v5 = h1[(size_t)p5.x*HH + lane];
    float v6 = h1[(size_t)p6.x*HH + lane];
    float v7 = h1[(size_t)p7.x*HH + lane];
    acc0 = fmaf(__int_as_float(p0.y), v0, acc0);
    acc1 = fmaf(__int_as_float(p1.y), v1, acc1);
    acc0 = fmaf(__int_as_float(p2.y), v2, acc0);
    acc1 = fmaf(__int_as_float(p3.y), v3, acc1);
    acc0 = fmaf(__int_as_float(p4.y), v4, acc0);
    acc1 = fmaf(__int_as_float(p5.y), v5, acc1);
    acc0 = fmaf(__int_as_float(p6.y), v6, acc0);
    acc1 = fmaf(__int_as_float(p7.y), v7, acc1);
  }
  for (; e < e1; ++e){
    int2 p = ef[e];
    acc0 = fmaf(__int_as_float(p.y), h1[(size_t)p.x*HH + lane], acc0);
  }
  sh[wv][lane] = acc0 + acc1;            // intra-wave LDS
  float hj = b2[lane];
  const float4* row = (const float4*)&sh[wv][0];
  #pragma unroll
  for (int i4 = 0; i4 < 16; ++i4){
    float4 v = row[i4];
    hj = fmaf(v.x, W2[(4*i4  )*HH + lane], hj);
    hj = fmaf(v.y, W2[(4*i4+1)*HH + lane], hj);
    hj = fmaf(v.z, W2[(4*i4+2)*HH + lane], hj);
    hj = fmaf(v.w, W2[(4*i4+3)*HH + lane], hj);
  }
  h2[(size_t)n*HH + lane] = fmaxf(hj, 0.f);
}

// ---------------- fused GRU step (v3, verified) ------------------------------
#define GRB 16
__launch_bounds__(384)
__global__ void k_gruf(const float* __restrict__ h2, const float* __restrict__ hprev,
                       const float* __restrict__ Wih, const float* __restrict__ Whh,
                       const float* __restrict__ bih, const float* __restrict__ bhh,
                       float* __restrict__ hnew, int ntiles){
  __shared__ float sh[2][GRB][64];   // [0]=h2 rows, [1]=hprev rows (8 KB)
  __shared__ float ex[6][GRB][64];   // gate exchange (24 KB)
  int tid = threadIdx.x, wv = tid >> 6, lane = tid & 63;
  int side = wv / 3;
  int gate = wv - side*3;
  const float* Wsel = side ? Whh : Wih;
  float bg = (side ? bhh : bih)[gate*64 + lane];
  float w[64];
  {
    const float* wr = Wsel + (size_t)(gate*64 + lane)*64;
    #pragma unroll
    for (int k = 0; k < 64; k += 4){
      float4 v = *(const float4*)(wr + k);
      w[k]=v.x; w[k+1]=v.y; w[k+2]=v.z; w[k+3]=v.w;
    }
  }

  for (int tile = blockIdx.x; tile < ntiles; tile += gridDim.x){
    int n0 = tile * GRB;
    __syncthreads();   // sh/ex free (previous epilogue done)
    for (int i = tid; i < 2*GRB*16; i += 384){
      if (i < GRB*16) ((float4*)sh)[i] = ((const float4*)(h2    + (size_t)n0*64))[i];
      else            ((float4*)sh)[i] = ((const float4*)(hprev + (size_t)n0*64))[i - GRB*16];
    }
    __syncthreads();

    float a[GRB];
    #pragma unroll
    for (int r0 = 0; r0 < GRB; r0 += 4){
      const float* h0 = &sh[side][r0    ][0];
      const float* h1p= &sh[side][r0 + 1][0];
      const float* h2p= &sh[side][r0 + 2][0];
      const float* h3 = &sh[side][r0 + 3][0];
      float s0=0.f, s1=0.f, s2=0.f, s3=0.f;
      #pragma unroll
      for (int k = 0; k < 64; k += 4){
        float4 v0 = *(const float4*)(h0 + k);
        float4 v1 = *(const float4*)(h1p + k);
        float4 v2 = *(const float4*)(h2p + k);
        float4 v3 = *(const float4*)(h3 + k);
        s0 = fmaf(v0.x, w[k], s0); s0 = fmaf(v0.y, w[k+1], s0);
        s0 = fmaf(v0.z, w[k+2], s0); s0 = fmaf(v0.w, w[k+3], s0);
        s1 = fmaf(v1.x, w[k], s1); s1 = fmaf(v1.y, w[k+1], s1);
        s1 = fmaf(v1.z, w[k+2], s1); s1 = fmaf(v1.w, w[k+3], s1);
        s2 = fmaf(v2.x, w[k], s2); s2 = fmaf(v2.y, w[k+1], s2);
        s2 = fmaf(v2.z, w[k+2], s2); s2 = fmaf(v2.w, w[k+3], s2);
        s3 = fmaf(v3.x, w[k], s3); s3 = fmaf(v3.y, w[k+1], s3);
        s3 = fmaf(v3.z, w[k+2], s3); s3 = fmaf(v3.w, w[k+3], s3);
      }
      a[r0]=s0; a[r0+1]=s1; a[r0+2]=s2; a[r0+3]=s3;
    }
    #pragma unroll
    for (int r = 0; r < GRB; ++r) ex[wv][r][lane] = a[r] + bg;
    __syncthreads();
    for (int i = tid; i < GRB*64; i += 384){
      int row = i >> 6, col = i & 63;
      float ir = ex[0][row][col], iz = ex[1][row][col], in_ = ex[2][row][col];
      float hr = ex[3][row][col], hz = ex[4][row][col], hn  = ex[5][row][col];
      float rg = 1.f/(1.f + expf(-(ir + hr)));
      float zg = 1.f/(1.f + expf(-(iz + hz)));
      float nv = tanhf(in_ + rg*hn);
      float hp = sh[1][row][col];
      hnew[(size_t)(n0 + row)*64 + col] = (1.f - zg)*nv + zg*hp;
    }
  }
}

// ---------------- head: logits = relu(h@Wc1+bc1)@Wc2 + bc2 ----------------
__global__ void k_head(const float* __restrict__ h, const float* __restrict__ Wc1,
                       const float* __restrict__ bc1, const float* __restrict__ Wc2,
                       const float* __restrict__ bc2, float* __restrict__ out){
  __shared__ float w1[64*32];
  __shared__ float w2[32];
  for (int i = threadIdx.x; i < 64*32; i += blockDim.x) w1[i] = Wc1[i];
  if (threadIdx.x < 32) w2[threadIdx.x] = Wc2[threadIdx.x];
  __syncthreads();
  int n = blockIdx.x*blockDim.x + threadIdx.x;
  if (n >= NN) return;
  const float* hr = h + (size_t)n*64;
  float hreg[64];
  #pragma unroll
  for (int k = 0; k < 64; ++k) hreg[k] = hr[k];
  float acc2 = bc2[0];
  #pragma unroll
  for (int c = 0; c < 32; ++c){
    float a = bc1[c];
    #pragma unroll
    for (int k = 0; k < 64; ++k) a = fmaf(hreg[k], w1[k*32 + c], a);
    a = fmaxf(a, 0.f);
    acc2 = fmaf(a, w2[c], acc2);
  }
  out[n] = acc2;
}

// ---------------- launch ----------------
extern "C" void kernel_launch(void* const* d_in, const int* in_sizes, int n_in,
                              void* d_out, int out_size, void* d_ws, size_t ws_size,
                              hipStream_t stream){
  const float* x    = (const float*)d_in[0];
  const int*   ei   = (const int*)  d_in[1];
  const float* W1   = (const float*)d_in[2];
  const float* b1   = (const float*)d_in[3];
  const float* W2   = (const float*)d_in[4];
  const float* b2   = (const float*)d_in[5];
  const float* W_ih = (const float*)d_in[6];
  const float* W_hh = (const float*)d_in[7];
  const float* b_ih = (const float*)d_in[8];
  const float* b_hh = (const float*)d_in[9];
  const float* Wc1  = (const float*)d_in[10];
  const float* bc1  = (const float*)d_in[11];
  const float* Wc2  = (const float*)d_in[12];
  const float* bc2  = (const float*)d_in[13];
  int E = in_sizes[1] / 2;
  const int* src = ei;
  const int* dst = ei + E;

  char* w = (char*)d_ws;
  auto alloc = [&](size_t bytes){ char* p = w; w += align256(bytes); return p; };
  int*   cnt  = (int*)  alloc((size_t)NN*4);
  int*   rp   = (int*)  alloc((size_t)(NN+1)*4);
  int*   cur  = (int*)  alloc((size_t)NN*4);
  float* dinv = (float*)alloc((size_t)NN*4);
  float* invd = (float*)alloc((size_t)NN*4);
  int2*  ef   = (int2*) alloc((size_t)E*8);
  float* h1   = (float*)alloc((size_t)NN*HH*4);
  float* h2   = (float*)alloc((size_t)NN*HH*4);
  float* hA   = (float*)alloc((size_t)NN*HH*4);
  float* hB   = (float*)alloc((size_t)NN*HH*4);
  if ((size_t)(w - (char*)d_ws) > ws_size) return;   // clean diagnostic fail

  hipMemsetAsync(cnt, 0, (size_t)NN*4, stream);
  hipMemsetAsync(cur, 0, (size_t)NN*4, stream);
  hipMemsetAsync(hA,  0, (size_t)NN*HH*4, stream);   // h0 = 0

  k_count<<<(E+255)/256, 256, 0, stream>>>(dst, E, cnt);
  k_dinv <<<(NN+255)/256, 256, 0, stream>>>(cnt, dinv, invd, NN);
  k_scan <<<1, SCAN_T, 0, stream>>>(cnt, rp, NN);
  k_fill <<<(E+255)/256, 256, 0, stream>>>(src, dst, E, rp, cur, dinv, ef);

  float* hprev = hA;
  float* hnext = hB;
  for (int t = 0; t < TT; ++t){
    const float* xt = x + (size_t)t*NN*FF;
    k_l1<<<(NN + 3)/4, 256, 0, stream>>>(xt, rp, ef, invd, W1, b1, h1);
    k_l2<<<(NN + 3)/4, 256, 0, stream>>>(h1, rp, ef, invd, W2, b2, h2);
    k_gruf<<<1024, 384, 0, stream>>>(h2, hprev, W_ih, W_hh, b_ih, b_hh, hnext, NN/GRB);
    float* tmp = hprev; hprev = hnext; hnext = tmp;
  }

  // after 12 swaps hprev == hA
  k_head<<<(NN + 255)/256, 256, 0, stream>>>(hprev, Wc1, bc1, Wc2, bc2, (float*)d_out);
}

// Round 11
// 2656.635 us; speedup vs baseline: 1.1582x; 1.0295x over previous
//
#include <hip/hip_runtime.h>
#include <hip/hip_bf16.h>
#include <math.h>

#define NN 50000
#define TT 12
#define FF 32
#define HH 64

static inline size_t align256(size_t x){ return (x + 255) & ~(size_t)255; }

// ---------------- graph preprocessing ----------------

__global__ void k_count(const int* __restrict__ dst, int E, int* __restrict__ cnt){
  int i = blockIdx.x*blockDim.x + threadIdx.x;
  if (i < E) atomicAdd(&cnt[dst[i]], 1);
}

__global__ void k_dinv(const int* __restrict__ cnt, float* __restrict__ dinv,
                       float* __restrict__ invd, int n){
  int i = blockIdx.x*blockDim.x + threadIdx.x;
  if (i < n){
    float d = (float)(cnt[i] + 1);            // +1 self loop
    dinv[i] = (float)(1.0 / sqrt((double)d));
    invd[i] = 1.0f / d;
  }
}

// ---- parallel prefix scan over cnt -> rp (exclusive), rp[n] = E ----
__global__ void k_bsum(const int* __restrict__ cnt, int* __restrict__ bsum, int n){
  __shared__ int s[256];
  int b = blockIdx.x, t = threadIdx.x;
  int i = b*256 + t;
  s[t] = (i < n) ? cnt[i] : 0;
  __syncthreads();
  for (int off = 128; off > 0; off >>= 1){
    if (t < off) s[t] += s[t + off];
    __syncthreads();
  }
  if (t == 0) bsum[b] = s[0];
}

__global__ void k_bscan(int* __restrict__ bsum, int nb){
  __shared__ int s[256];
  int t = threadIdx.x;
  s[t] = (t < nb) ? bsum[t] : 0;
  __syncthreads();
  for (int off = 1; off < 256; off <<= 1){
    int v = (t >= off) ? s[t - off] : 0;
    __syncthreads();
    s[t] += v;
    __syncthreads();
  }
  if (t < nb) bsum[t] = (t == 0) ? 0 : s[t-1];   // exclusive
}

__global__ void k_bput(const int* __restrict__ cnt, const int* __restrict__ bsum,
                       int* __restrict__ rp, int n){
  __shared__ int s[256];
  int b = blockIdx.x, t = threadIdx.x;
  int i = b*256 + t;
  int v = (i < n) ? cnt[i] : 0;
  s[t] = v;
  __syncthreads();
  for (int off = 1; off < 256; off <<= 1){
    int u = (t >= off) ? s[t - off] : 0;
    __syncthreads();
    s[t] += u;
    __syncthreads();
  }
  int incl = s[t];
  if (i < n)  rp[i] = bsum[b] + incl - v;
  if (i == n-1) rp[n] = bsum[b] + incl;          // total = E
}

// packed edge record: .x = src index, .y = norm (float bits). ONE 8B scatter.
__global__ void k_fill(const int* __restrict__ src, const int* __restrict__ dst, int E,
                       const int* __restrict__ rp, int* __restrict__ cur,
                       const float* __restrict__ dinv,
                       int2* __restrict__ ef){
  int i = blockIdx.x*blockDim.x + threadIdx.x;
  if (i < E){
    int d = dst[i], s = src[i];
    int pos = rp[d] + atomicAdd(&cur[d], 1);
    int2 rec; rec.x = s; rec.y = __float_as_int(dinv[s] * dinv[d]);
    ef[pos] = rec;
  }
}

// ---------------- fused layer 1: h1 = relu( (A x_t) W1 + b1 ) ---------------
__launch_bounds__(256)
__global__ void k_l1(const float* __restrict__ xt, const int* __restrict__ rp,
                     const int2* __restrict__ ef, const float* __restrict__ invd,
                     const float* __restrict__ W1, const float* __restrict__ b1,
                     float* __restrict__ h1){
  __shared__ float sh[4][2][32];
  int wv = threadIdx.x >> 6, lane = threadIdx.x & 63;
  int n = blockIdx.x*4 + wv;
  if (n >= NN) return;
  int half = lane >> 5, f = lane & 31;

  float acc0 = half ? 0.f : invd[n] * xt[(size_t)n*FF + f];
  float acc1 = 0.f;
  int e = rp[n] + half, e1 = rp[n+1];
  for (; e + 6 < e1; e += 8){                 // 4 edges per half per iter
    int2 p0 = ef[e], p1 = ef[e+2], p2 = ef[e+4], p3 = ef[e+6];
    float v0 = xt[(size_t)p0.x*FF + f];
    float v1 = xt[(size_t)p1.x*FF + f];
    float v2 = xt[(size_t)p2.x*FF + f];
    float v3 = xt[(size_t)p3.x*FF + f];
    acc0 = fmaf(__int_as_float(p0.y), v0, acc0);
    acc1 = fmaf(__int_as_float(p1.y), v1, acc1);
    acc0 = fmaf(__int_as_float(p2.y), v2, acc0);
    acc1 = fmaf(__int_as_float(p3.y), v3, acc1);
  }
  for (; e < e1; e += 2){
    int2 p = ef[e];
    acc0 = fmaf(__int_as_float(p.y), xt[(size_t)p.x*FF + f], acc0);
  }
  float acc = acc0 + acc1;
  sh[wv][half][f] = acc;                 // intra-wave LDS (lockstep)
  if (lane < 32) sh[wv][0][f] = acc + sh[wv][1][f];
  float hj = b1[lane];
  const float4* row = (const float4*)&sh[wv][0][0];
  #pragma unroll
  for (int i4 = 0; i4 < 8; ++i4){
    float4 v = row[i4];                  // same-addr broadcast
    hj = fmaf(v.x, W1[(4*i4  )*HH + lane], hj);
    hj = fmaf(v.y, W1[(4*i4+1)*HH + lane], hj);
    hj = fmaf(v.z, W1[(4*i4+2)*HH + lane], hj);
    hj = fmaf(v.w, W1[(4*i4+3)*HH + lane], hj);
  }
  h1[(size_t)n*HH + lane] = fmaxf(hj, 0.f);
}

// ---------------- fused layer 2: h2 = relu( (A h1) W2 + b2 ) ----------------
__launch_bounds__(256)
__global__ void k_l2(const float* __restrict__ h1, const int* __restrict__ rp,
                     const int2* __restrict__ ef, const float* __restrict__ invd,
                     const float* __restrict__ W2, const float* __restrict__ b2,
                     float* __restrict__ h2){
  __shared__ float sh[4][64];
  int wv = threadIdx.x >> 6, lane = threadIdx.x & 63;
  int n = blockIdx.x*4 + wv;
  if (n >= NN) return;

  float acc0 = invd[n] * h1[(size_t)n*HH + lane];
  float acc1 = 0.f;
  int e = rp[n], e1 = rp[n+1];
  for (; e + 8 <= e1; e += 8){
    int2 p0 = ef[e  ], p1 = ef[e+1], p2 = ef[e+2], p3 = ef[e+3];
    int2 p4 = ef[e+4], p5 = ef[e+5], p6 = ef[e+6], p7 = ef[e+7];
    float v0 = h1[(size_t)p0.x*HH + lane];
    float v1 = h1[(size_t)p1.x*HH + lane];
    float v2 = h1[(size_t)p2.x*HH + lane];
    float v3 = h1[(size_t)p3.x*HH + lane];
    float v4 = h1[(size_t)p4.x*HH + lane];
    float v5 = h1[(size_t)p5.x*HH + lane];
    float v6 = h1[(size_t)p6.x*HH + lane];
    float v7 = h1[(size_t)p7.x*HH + lane];
    acc0 = fmaf(__int_as_float(p0.y), v0, acc0);
    acc1 = fmaf(__int_as_float(p1.y), v1, acc1);
    acc0 = fmaf(__int_as_float(p2.y), v2, acc0);
    acc1 = fmaf(__int_as_float(p3.y), v3, acc1);
    acc0 = fmaf(__int_as_float(p4.y), v4, acc0);
    acc1 = fmaf(__int_as_float(p5.y), v5, acc1);
    acc0 = fmaf(__int_as_float(p6.y), v6, acc0);
    acc1 = fmaf(__int_as_float(p7.y), v7, acc1);
  }
  for (; e < e1; ++e){
    int2 p = ef[e];
    acc0 = fmaf(__int_as_float(p.y), h1[(size_t)p.x*HH + lane], acc0);
  }
  sh[wv][lane] = acc0 + acc1;            // intra-wave LDS
  float hj = b2[lane];
  const float4* row = (const float4*)&sh[wv][0];
  #pragma unroll
  for (int i4 = 0; i4 < 16; ++i4){
    float4 v = row[i4];
    hj = fmaf(v.x, W2[(4*i4  )*HH + lane], hj);
    hj = fmaf(v.y, W2[(4*i4+1)*HH + lane], hj);
    hj = fmaf(v.z, W2[(4*i4+2)*HH + lane], hj);
    hj = fmaf(v.w, W2[(4*i4+3)*HH + lane], hj);
  }
  h2[(size_t)n*HH + lane] = fmaxf(hj, 0.f);
}

// ---------------- fused GRU step (v3, verified) ------------------------------
#define GRB 16
__launch_bounds__(384)
__global__ void k_gruf(const float* __restrict__ h2, const float* __restrict__ hprev,
                       const float* __restrict__ Wih, const float* __restrict__ Whh,
                       const float* __restrict__ bih, const float* __restrict__ bhh,
                       float* __restrict__ hnew, int ntiles){
  __shared__ float sh[2][GRB][64];   // [0]=h2 rows, [1]=hprev rows (8 KB)
  __shared__ float ex[6][GRB][64];   // gate exchange (24 KB)
  int tid = threadIdx.x, wv = tid >> 6, lane = tid & 63;
  int side = wv / 3;
  int gate = wv - side*3;
  const float* Wsel = side ? Whh : Wih;
  float bg = (side ? bhh : bih)[gate*64 + lane];
  float w[64];
  {
    const float* wr = Wsel + (size_t)(gate*64 + lane)*64;
    #pragma unroll
    for (int k = 0; k < 64; k += 4){
      float4 v = *(const float4*)(wr + k);
      w[k]=v.x; w[k+1]=v.y; w[k+2]=v.z; w[k+3]=v.w;
    }
  }

  for (int tile = blockIdx.x; tile < ntiles; tile += gridDim.x){
    int n0 = tile * GRB;
    __syncthreads();   // sh/ex free (previous epilogue done)
    for (int i = tid; i < 2*GRB*16; i += 384){
      if (i < GRB*16) ((float4*)sh)[i] = ((const float4*)(h2    + (size_t)n0*64))[i];
      else            ((float4*)sh)[i] = ((const float4*)(hprev + (size_t)n0*64))[i - GRB*16];
    }
    __syncthreads();

    float a[GRB];
    #pragma unroll
    for (int r0 = 0; r0 < GRB; r0 += 4){
      const float* h0 = &sh[side][r0    ][0];
      const float* h1p= &sh[side][r0 + 1][0];
      const float* h2p= &sh[side][r0 + 2][0];
      const float* h3 = &sh[side][r0 + 3][0];
      float s0=0.f, s1=0.f, s2=0.f, s3=0.f;
      #pragma unroll
      for (int k = 0; k < 64; k += 4){
        float4 v0 = *(const float4*)(h0 + k);
        float4 v1 = *(const float4*)(h1p + k);
        float4 v2 = *(const float4*)(h2p + k);
        float4 v3 = *(const float4*)(h3 + k);
        s0 = fmaf(v0.x, w[k], s0); s0 = fmaf(v0.y, w[k+1], s0);
        s0 = fmaf(v0.z, w[k+2], s0); s0 = fmaf(v0.w, w[k+3], s0);
        s1 = fmaf(v1.x, w[k], s1); s1 = fmaf(v1.y, w[k+1], s1);
        s1 = fmaf(v1.z, w[k+2], s1); s1 = fmaf(v1.w, w[k+3], s1);
        s2 = fmaf(v2.x, w[k], s2); s2 = fmaf(v2.y, w[k+1], s2);
        s2 = fmaf(v2.z, w[k+2], s2); s2 = fmaf(v2.w, w[k+3], s2);
        s3 = fmaf(v3.x, w[k], s3); s3 = fmaf(v3.y, w[k+1], s3);
        s3 = fmaf(v3.z, w[k+2], s3); s3 = fmaf(v3.w, w[k+3], s3);
      }
      a[r0]=s0; a[r0+1]=s1; a[r0+2]=s2; a[r0+3]=s3;
    }
    #pragma unroll
    for (int r = 0; r < GRB; ++r) ex[wv][r][lane] = a[r] + bg;
    __syncthreads();
    for (int i = tid; i < GRB*64; i += 384){
      int row = i >> 6, col = i & 63;
      float ir = ex[0][row][col], iz = ex[1][row][col], in_ = ex[2][row][col];
      float hr = ex[3][row][col], hz = ex[4][row][col], hn  = ex[5][row][col];
      float rg = 1.f/(1.f + expf(-(ir + hr)));
      float zg = 1.f/(1.f + expf(-(iz + hz)));
      float nv = tanhf(in_ + rg*hn);
      float hp = sh[1][row][col];
      hnew[(size_t)(n0 + row)*64 + col] = (1.f - zg)*nv + zg*hp;
    }
  }
}

// ---------------- head: logits = relu(h@Wc1+bc1)@Wc2 + bc2 ----------------
__global__ void k_head(const float* __restrict__ h, const float* __restrict__ Wc1,
                       const float* __restrict__ bc1, const float* __restrict__ Wc2,
                       const float* __restrict__ bc2, float* __restrict__ out){
  __shared__ float w1[64*32];
  __shared__ float w2[32];
  for (int i = threadIdx.x; i < 64*32; i += blockDim.x) w1[i] = Wc1[i];
  if (threadIdx.x < 32) w2[threadIdx.x] = Wc2[threadIdx.x];
  __syncthreads();
  int n = blockIdx.x*blockDim.x + threadIdx.x;
  if (n >= NN) return;
  const float* hr = h + (size_t)n*64;
  float hreg[64];
  #pragma unroll
  for (int k = 0; k < 64; ++k) hreg[k] = hr[k];
  float acc2 = bc2[0];
  #pragma unroll
  for (int c = 0; c < 32; ++c){
    float a = bc1[c];
    #pragma unroll
    for (int k = 0; k < 64; ++k) a = fmaf(hreg[k], w1[k*32 + c], a);
    a = fmaxf(a, 0.f);
    acc2 = fmaf(a, w2[c], acc2);
  }
  out[n] = acc2;
}

// ---------------- launch ----------------
extern "C" void kernel_launch(void* const* d_in, const int* in_sizes, int n_in,
                              void* d_out, int out_size, void* d_ws, size_t ws_size,
                              hipStream_t stream){
  const float* x    = (const float*)d_in[0];
  const int*   ei   = (const int*)  d_in[1];
  const float* W1   = (const float*)d_in[2];
  const float* b1   = (const float*)d_in[3];
  const float* W2   = (const float*)d_in[4];
  const float* b2   = (const float*)d_in[5];
  const float* W_ih = (const float*)d_in[6];
  const float* W_hh = (const float*)d_in[7];
  const float* b_ih = (const float*)d_in[8];
  const float* b_hh = (const float*)d_in[9];
  const float* Wc1  = (const float*)d_in[10];
  const float* bc1  = (const float*)d_in[11];
  const float* Wc2  = (const float*)d_in[12];
  const float* bc2  = (const float*)d_in[13];
  int E = in_sizes[1] / 2;
  const int* src = ei;
  const int* dst = ei + E;
  int NB = (NN + 255)/256;   // 196 scan blocks

  char* w = (char*)d_ws;
  auto alloc = [&](size_t bytes){ char* p = w; w += align256(bytes); return p; };
  int*   cnt  = (int*)  alloc((size_t)NN*4);
  int*   rp   = (int*)  alloc((size_t)(NN+1)*4);
  int*   cur  = (int*)  alloc((size_t)NN*4);
  int*   bsum = (int*)  alloc((size_t)NB*4);
  float* dinv = (float*)alloc((size_t)NN*4);
  float* invd = (float*)alloc((size_t)NN*4);
  int2*  ef   = (int2*) alloc((size_t)E*8);
  float* h1   = (float*)alloc((size_t)NN*HH*4);
  float* h2   = (float*)alloc((size_t)NN*HH*4);
  float* hA   = (float*)alloc((size_t)NN*HH*4);
  float* hB   = (float*)alloc((size_t)NN*HH*4);
  if ((size_t)(w - (char*)d_ws) > ws_size) return;   // clean diagnostic fail

  hipMemsetAsync(cnt, 0, (size_t)NN*4, stream);
  hipMemsetAsync(cur, 0, (size_t)NN*4, stream);
  hipMemsetAsync(hA,  0, (size_t)NN*HH*4, stream);   // h0 = 0

  k_count<<<(E+255)/256, 256, 0, stream>>>(dst, E, cnt);
  k_dinv <<<(NN+255)/256, 256, 0, stream>>>(cnt, dinv, invd, NN);
  k_bsum <<<NB, 256, 0, stream>>>(cnt, bsum, NN);
  k_bscan<<<1, 256, 0, stream>>>(bsum, NB);
  k_bput <<<NB, 256, 0, stream>>>(cnt, bsum, rp, NN);
  k_fill <<<(E+255)/256, 256, 0, stream>>>(src, dst, E, rp, cur, dinv, ef);

  float* hprev = hA;
  float* hnext = hB;
  for (int t = 0; t < TT; ++t){
    const float* xt = x + (size_t)t*NN*FF;
    k_l1<<<(NN + 3)/4, 256, 0, stream>>>(xt, rp, ef, invd, W1, b1, h1);
    k_l2<<<(NN + 3)/4, 256, 0, stream>>>(h1, rp, ef, invd, W2, b2, h2);
    k_gruf<<<1024, 384, 0, stream>>>(h2, hprev, W_ih, W_hh, b_ih, b_hh, hnext, NN/GRB);
    float* tmp = hprev; hprev = hnext; hnext = tmp;
  }

  // after 12 swaps hprev == hA
  k_head<<<(NN + 255)/256, 256, 0, stream>>>(hprev, Wc1, bc1, Wc2, bc2, (float*)d_out);
}

// Round 12
// 2570.688 us; speedup vs baseline: 1.1970x; 1.0334x over previous
//
#include <hip/hip_runtime.h>
#include <hip/hip_bf16.h>
#include <math.h>

#define NN 50000
#define TT 12
#define FF 32
#define HH 64

static inline size_t align256(size_t x){ return (x + 255) & ~(size_t)255; }

// ---------------- graph preprocessing ----------------

__global__ void k_count(const int* __restrict__ dst, int E, int* __restrict__ cnt){
  int i = blockIdx.x*blockDim.x + threadIdx.x;
  if (i < E) atomicAdd(&cnt[dst[i]], 1);
}

__global__ void k_dinv(const int* __restrict__ cnt, float* __restrict__ dinv,
                       float* __restrict__ invd, int n){
  int i = blockIdx.x*blockDim.x + threadIdx.x;
  if (i < n){
    float d = (float)(cnt[i] + 1);            // +1 self loop
    dinv[i] = (float)(1.0 / sqrt((double)d));
    invd[i] = 1.0f / d;
  }
}

// ---- parallel prefix scan over cnt -> rp (exclusive), rp[n] = E ----
__global__ void k_bsum(const int* __restrict__ cnt, int* __restrict__ bsum, int n){
  __shared__ int s[256];
  int b = blockIdx.x, t = threadIdx.x;
  int i = b*256 + t;
  s[t] = (i < n) ? cnt[i] : 0;
  __syncthreads();
  for (int off = 128; off > 0; off >>= 1){
    if (t < off) s[t] += s[t + off];
    __syncthreads();
  }
  if (t == 0) bsum[b] = s[0];
}

__global__ void k_bscan(int* __restrict__ bsum, int nb){
  __shared__ int s[256];
  int t = threadIdx.x;
  s[t] = (t < nb) ? bsum[t] : 0;
  __syncthreads();
  for (int off = 1; off < 256; off <<= 1){
    int v = (t >= off) ? s[t - off] : 0;
    __syncthreads();
    s[t] += v;
    __syncthreads();
  }
  if (t < nb) bsum[t] = (t == 0) ? 0 : s[t-1];   // exclusive
}

__global__ void k_bput(const int* __restrict__ cnt, const int* __restrict__ bsum,
                       int* __restrict__ rp, int n){
  __shared__ int s[256];
  int b = blockIdx.x, t = threadIdx.x;
  int i = b*256 + t;
  int v = (i < n) ? cnt[i] : 0;
  s[t] = v;
  __syncthreads();
  for (int off = 1; off < 256; off <<= 1){
    int u = (t >= off) ? s[t - off] : 0;
    __syncthreads();
    s[t] += u;
    __syncthreads();
  }
  int incl = s[t];
  if (i < n)  rp[i] = bsum[b] + incl - v;
  if (i == n-1) rp[n] = bsum[b] + incl;          // total = E
}

// packed edge record: .x = src index, .y = norm (float bits). ONE 8B scatter.
__global__ void k_fill(const int* __restrict__ src, const int* __restrict__ dst, int E,
                       const int* __restrict__ rp, int* __restrict__ cur,
                       const float* __restrict__ dinv,
                       int2* __restrict__ ef){
  int i = blockIdx.x*blockDim.x + threadIdx.x;
  if (i < E){
    int d = dst[i], s = src[i];
    int pos = rp[d] + atomicAdd(&cur[d], 1);
    int2 rec; rec.x = s; rec.y = __float_as_int(dinv[s] * dinv[d]);
    ef[pos] = rec;
  }
}

// ---------------- fused layer 1: h1 = relu( (A x_t) W1 + b1 ) ---------------
__launch_bounds__(256)
__global__ void k_l1(const float* __restrict__ xt, const int* __restrict__ rp,
                     const int2* __restrict__ ef, const float* __restrict__ invd,
                     const float* __restrict__ W1, const float* __restrict__ b1,
                     float* __restrict__ h1){
  __shared__ float sh[4][2][32];
  int wv = threadIdx.x >> 6, lane = threadIdx.x & 63;
  int n = blockIdx.x*4 + wv;
  if (n >= NN) return;
  int half = lane >> 5, f = lane & 31;

  float acc0 = half ? 0.f : invd[n] * xt[(size_t)n*FF + f];
  float acc1 = 0.f;
  int e = rp[n] + half, e1 = rp[n+1];
  for (; e + 6 < e1; e += 8){                 // 4 edges per half per iter
    int2 p0 = ef[e], p1 = ef[e+2], p2 = ef[e+4], p3 = ef[e+6];
    float v0 = xt[(size_t)p0.x*FF + f];
    float v1 = xt[(size_t)p1.x*FF + f];
    float v2 = xt[(size_t)p2.x*FF + f];
    float v3 = xt[(size_t)p3.x*FF + f];
    acc0 = fmaf(__int_as_float(p0.y), v0, acc0);
    acc1 = fmaf(__int_as_float(p1.y), v1, acc1);
    acc0 = fmaf(__int_as_float(p2.y), v2, acc0);
    acc1 = fmaf(__int_as_float(p3.y), v3, acc1);
  }
  for (; e < e1; e += 2){
    int2 p = ef[e];
    acc0 = fmaf(__int_as_float(p.y), xt[(size_t)p.x*FF + f], acc0);
  }
  float acc = acc0 + acc1;
  sh[wv][half][f] = acc;                 // intra-wave LDS (lockstep)
  if (lane < 32) sh[wv][0][f] = acc + sh[wv][1][f];
  float hj = b1[lane];
  const float4* row = (const float4*)&sh[wv][0][0];
  #pragma unroll
  for (int i4 = 0; i4 < 8; ++i4){
    float4 v = row[i4];                  // same-addr broadcast
    hj = fmaf(v.x, W1[(4*i4  )*HH + lane], hj);
    hj = fmaf(v.y, W1[(4*i4+1)*HH + lane], hj);
    hj = fmaf(v.z, W1[(4*i4+2)*HH + lane], hj);
    hj = fmaf(v.w, W1[(4*i4+3)*HH + lane], hj);
  }
  h1[(size_t)n*HH + lane] = fmaxf(hj, 0.f);
}

// ---------------- fused layer 2: h2 = relu( (A h1) W2 + b2 ) ----------------
__launch_bounds__(256)
__global__ void k_l2(const float* __restrict__ h1, const int* __restrict__ rp,
                     const int2* __restrict__ ef, const float* __restrict__ invd,
                     const float* __restrict__ W2, const float* __restrict__ b2,
                     float* __restrict__ h2){
  __shared__ float sh[4][64];
  int wv = threadIdx.x >> 6, lane = threadIdx.x & 63;
  int n = blockIdx.x*4 + wv;
  if (n >= NN) return;

  float acc0 = invd[n] * h1[(size_t)n*HH + lane];
  float acc1 = 0.f;
  int e = rp[n], e1 = rp[n+1];
  for (; e + 8 <= e1; e += 8){
    int2 p0 = ef[e  ], p1 = ef[e+1], p2 = ef[e+2], p3 = ef[e+3];
    int2 p4 = ef[e+4], p5 = ef[e+5], p6 = ef[e+6], p7 = ef[e+7];
    float v0 = h1[(size_t)p0.x*HH + lane];
    float v1 = h1[(size_t)p1.x*HH + lane];
    float v2 = h1[(size_t)p2.x*HH + lane];
    float v3 = h1[(size_t)p3.x*HH + lane];
    float v4 = h1[(size_t)p4.x*HH + lane];
    float v5 = h1[(size_t)p5.x*HH + lane];
    float v6 = h1[(size_t)p6.x*HH + lane];
    float v7 = h1[(size_t)p7.x*HH + lane];
    acc0 = fmaf(__int_as_float(p0.y), v0, acc0);
    acc1 = fmaf(__int_as_float(p1.y), v1, acc1);
    acc0 = fmaf(__int_as_float(p2.y), v2, acc0);
    acc1 = fmaf(__int_as_float(p3.y), v3, acc1);
    acc0 = fmaf(__int_as_float(p4.y), v4, acc0);
    acc1 = fmaf(__int_as_float(p5.y), v5, acc1);
    acc0 = fmaf(__int_as_float(p6.y), v6, acc0);
    acc1 = fmaf(__int_as_float(p7.y), v7, acc1);
  }
  for (; e < e1; ++e){
    int2 p = ef[e];
    acc0 = fmaf(__int_as_float(p.y), h1[(size_t)p.x*HH + lane], acc0);
  }
  sh[wv][lane] = acc0 + acc1;            // intra-wave LDS
  float hj = b2[lane];
  const float4* row = (const float4*)&sh[wv][0];
  #pragma unroll
  for (int i4 = 0; i4 < 16; ++i4){
    float4 v = row[i4];
    hj = fmaf(v.x, W2[(4*i4  )*HH + lane], hj);
    hj = fmaf(v.y, W2[(4*i4+1)*HH + lane], hj);
    hj = fmaf(v.z, W2[(4*i4+2)*HH + lane], hj);
    hj = fmaf(v.w, W2[(4*i4+3)*HH + lane], hj);
  }
  h2[(size_t)n*HH + lane] = fmaxf(hj, 0.f);
}

// ---------------- fused GRU step, v4: one 16-node tile per block -------------
// grid = NN/GRB = 3125 blocks, no grid-stride (kills 3-vs-4-tile tail
// imbalance that capped occupancy at 22%). Block co-residency provides the
// stage/compute overlap the loop version lacked.
#define GRB 16
__launch_bounds__(384)
__global__ void k_gruf(const float* __restrict__ h2, const float* __restrict__ hprev,
                       const float* __restrict__ Wih, const float* __restrict__ Whh,
                       const float* __restrict__ bih, const float* __restrict__ bhh,
                       float* __restrict__ hnew){
  __shared__ float sh[2][GRB][64];   // [0]=h2 rows, [1]=hprev rows (8 KB)
  __shared__ float ex[6][GRB][64];   // gate exchange (24 KB)
  int tid = threadIdx.x, wv = tid >> 6, lane = tid & 63;
  int side = wv / 3;
  int gate = wv - side*3;
  int n0 = blockIdx.x * GRB;

  // stage h tile FIRST (deepest in vmcnt queue), then weights
  for (int i = tid; i < 2*GRB*16; i += 384){
    if (i < GRB*16) ((float4*)sh)[i] = ((const float4*)(h2    + (size_t)n0*64))[i];
    else            ((float4*)sh)[i] = ((const float4*)(hprev + (size_t)n0*64))[i - GRB*16];
  }
  const float* Wsel = side ? Whh : Wih;
  float bg = (side ? bhh : bih)[gate*64 + lane];
  float w[64];
  {
    const float* wr = Wsel + (size_t)(gate*64 + lane)*64;
    #pragma unroll
    for (int k = 0; k < 64; k += 4){
      float4 v = *(const float4*)(wr + k);
      w[k]=v.x; w[k+1]=v.y; w[k+2]=v.z; w[k+3]=v.w;
    }
  }
  __syncthreads();

  float a[GRB];
  #pragma unroll
  for (int r0 = 0; r0 < GRB; r0 += 4){
    const float* h0 = &sh[side][r0    ][0];
    const float* h1p= &sh[side][r0 + 1][0];
    const float* h2p= &sh[side][r0 + 2][0];
    const float* h3 = &sh[side][r0 + 3][0];
    float s0=0.f, s1=0.f, s2=0.f, s3=0.f;
    #pragma unroll
    for (int k = 0; k < 64; k += 4){
      float4 v0 = *(const float4*)(h0 + k);    // LDS same-addr broadcast
      float4 v1 = *(const float4*)(h1p + k);
      float4 v2 = *(const float4*)(h2p + k);
      float4 v3 = *(const float4*)(h3 + k);
      s0 = fmaf(v0.x, w[k], s0); s0 = fmaf(v0.y, w[k+1], s0);
      s0 = fmaf(v0.z, w[k+2], s0); s0 = fmaf(v0.w, w[k+3], s0);
      s1 = fmaf(v1.x, w[k], s1); s1 = fmaf(v1.y, w[k+1], s1);
      s1 = fmaf(v1.z, w[k+2], s1); s1 = fmaf(v1.w, w[k+3], s1);
      s2 = fmaf(v2.x, w[k], s2); s2 = fmaf(v2.y, w[k+1], s2);
      s2 = fmaf(v2.z, w[k+2], s2); s2 = fmaf(v2.w, w[k+3], s2);
      s3 = fmaf(v3.x, w[k], s3); s3 = fmaf(v3.y, w[k+1], s3);
      s3 = fmaf(v3.z, w[k+2], s3); s3 = fmaf(v3.w, w[k+3], s3);
    }
    a[r0]=s0; a[r0+1]=s1; a[r0+2]=s2; a[r0+3]=s3;
  }
  #pragma unroll
  for (int r = 0; r < GRB; ++r) ex[wv][r][lane] = a[r] + bg;
  __syncthreads();
  for (int i = tid; i < GRB*64; i += 384){
    int row = i >> 6, col = i & 63;
    float ir = ex[0][row][col], iz = ex[1][row][col], in_ = ex[2][row][col];
    float hr = ex[3][row][col], hz = ex[4][row][col], hn  = ex[5][row][col];
    float rg = 1.f/(1.f + expf(-(ir + hr)));
    float zg = 1.f/(1.f + expf(-(iz + hz)));
    float nv = tanhf(in_ + rg*hn);
    float hp = sh[1][row][col];
    hnew[(size_t)(n0 + row)*64 + col] = (1.f - zg)*nv + zg*hp;
  }
}

// ---------------- head: logits = relu(h@Wc1+bc1)@Wc2 + bc2 ----------------
__global__ void k_head(const float* __restrict__ h, const float* __restrict__ Wc1,
                       const float* __restrict__ bc1, const float* __restrict__ Wc2,
                       const float* __restrict__ bc2, float* __restrict__ out){
  __shared__ float w1[64*32];
  __shared__ float w2[32];
  for (int i = threadIdx.x; i < 64*32; i += blockDim.x) w1[i] = Wc1[i];
  if (threadIdx.x < 32) w2[threadIdx.x] = Wc2[threadIdx.x];
  __syncthreads();
  int n = blockIdx.x*blockDim.x + threadIdx.x;
  if (n >= NN) return;
  const float* hr = h + (size_t)n*64;
  float hreg[64];
  #pragma unroll
  for (int k = 0; k < 64; ++k) hreg[k] = hr[k];
  float acc2 = bc2[0];
  #pragma unroll
  for (int c = 0; c < 32; ++c){
    float a = bc1[c];
    #pragma unroll
    for (int k = 0; k < 64; ++k) a = fmaf(hreg[k], w1[k*32 + c], a);
    a = fmaxf(a, 0.f);
    acc2 = fmaf(a, w2[c], acc2);
  }
  out[n] = acc2;
}

// ---------------- launch ----------------
extern "C" void kernel_launch(void* const* d_in, const int* in_sizes, int n_in,
                              void* d_out, int out_size, void* d_ws, size_t ws_size,
                              hipStream_t stream){
  const float* x    = (const float*)d_in[0];
  const int*   ei   = (const int*)  d_in[1];
  const float* W1   = (const float*)d_in[2];
  const float* b1   = (const float*)d_in[3];
  const float* W2   = (const float*)d_in[4];
  const float* b2   = (const float*)d_in[5];
  const float* W_ih = (const float*)d_in[6];
  const float* W_hh = (const float*)d_in[7];
  const float* b_ih = (const float*)d_in[8];
  const float* b_hh = (const float*)d_in[9];
  const float* Wc1  = (const float*)d_in[10];
  const float* bc1  = (const float*)d_in[11];
  const float* Wc2  = (const float*)d_in[12];
  const float* bc2  = (const float*)d_in[13];
  int E = in_sizes[1] / 2;
  const int* src = ei;
  const int* dst = ei + E;
  int NB = (NN + 255)/256;   // 196 scan blocks

  char* w = (char*)d_ws;
  auto alloc = [&](size_t bytes){ char* p = w; w += align256(bytes); return p; };
  int*   cnt  = (int*)  alloc((size_t)NN*4);
  int*   rp   = (int*)  alloc((size_t)(NN+1)*4);
  int*   cur  = (int*)  alloc((size_t)NN*4);
  int*   bsum = (int*)  alloc((size_t)NB*4);
  float* dinv = (float*)alloc((size_t)NN*4);
  float* invd = (float*)alloc((size_t)NN*4);
  int2*  ef   = (int2*) alloc((size_t)E*8);
  float* h1   = (float*)alloc((size_t)NN*HH*4);
  float* h2   = (float*)alloc((size_t)NN*HH*4);
  float* hA   = (float*)alloc((size_t)NN*HH*4);
  float* hB   = (float*)alloc((size_t)NN*HH*4);
  if ((size_t)(w - (char*)d_ws) > ws_size) return;   // clean diagnostic fail

  hipMemsetAsync(cnt, 0, (size_t)NN*4, stream);
  hipMemsetAsync(cur, 0, (size_t)NN*4, stream);
  hipMemsetAsync(hA,  0, (size_t)NN*HH*4, stream);   // h0 = 0

  k_count<<<(E+255)/256, 256, 0, stream>>>(dst, E, cnt);
  k_dinv <<<(NN+255)/256, 256, 0, stream>>>(cnt, dinv, invd, NN);
  k_bsum <<<NB, 256, 0, stream>>>(cnt, bsum, NN);
  k_bscan<<<1, 256, 0, stream>>>(bsum, NB);
  k_bput <<<NB, 256, 0, stream>>>(cnt, bsum, rp, NN);
  k_fill <<<(E+255)/256, 256, 0, stream>>>(src, dst, E, rp, cur, dinv, ef);

  float* hprev = hA;
  float* hnext = hB;
  for (int t = 0; t < TT; ++t){
    const float* xt = x + (size_t)t*NN*FF;
    k_l1<<<(NN + 3)/4, 256, 0, stream>>>(xt, rp, ef, invd, W1, b1, h1);
    k_l2<<<(NN + 3)/4, 256, 0, stream>>>(h1, rp, ef, invd, W2, b2, h2);
    k_gruf<<<NN/GRB, 384, 0, stream>>>(h2, hprev, W_ih, W_hh, b_ih, b_hh, hnext);
    float* tmp = hprev; hprev = hnext; hnext = tmp;
  }

  // after 12 swaps hprev == hA
  k_head<<<(NN + 255)/256, 256, 0, stream>>>(hprev, Wc1, bc1, Wc2, bc2, (float*)d_out);
}

// Round 14
// 2518.554 us; speedup vs baseline: 1.2217x; 1.0207x over previous
//
#include <hip/hip_runtime.h>
#include <hip/hip_bf16.h>
#include <math.h>

#define NN 50000
#define TT 12
#define FF 32
#define HH 64

static inline size_t align256(size_t x){ return (x + 255) & ~(size_t)255; }

// ---------------- graph preprocessing ----------------

__global__ void k_count(const int* __restrict__ dst, int E, int* __restrict__ cnt){
  int i = blockIdx.x*blockDim.x + threadIdx.x;
  if (i < E) atomicAdd(&cnt[dst[i]], 1);
}

__global__ void k_dinv(const int* __restrict__ cnt, float* __restrict__ dinv,
                       float* __restrict__ invd, int n){
  int i = blockIdx.x*blockDim.x + threadIdx.x;
  if (i < n){
    float d = (float)(cnt[i] + 1);            // +1 self loop
    dinv[i] = (float)(1.0 / sqrt((double)d));
    invd[i] = 1.0f / d;
  }
}

// ---- parallel prefix scan over cnt -> rp (exclusive), rp[n] = E ----
__global__ void k_bsum(const int* __restrict__ cnt, int* __restrict__ bsum, int n){
  __shared__ int s[256];
  int b = blockIdx.x, t = threadIdx.x;
  int i = b*256 + t;
  s[t] = (i < n) ? cnt[i] : 0;
  __syncthreads();
  for (int off = 128; off > 0; off >>= 1){
    if (t < off) s[t] += s[t + off];
    __syncthreads();
  }
  if (t == 0) bsum[b] = s[0];
}

__global__ void k_bscan(int* __restrict__ bsum, int nb){
  __shared__ int s[256];
  int t = threadIdx.x;
  s[t] = (t < nb) ? bsum[t] : 0;
  __syncthreads();
  for (int off = 1; off < 256; off <<= 1){
    int v = (t >= off) ? s[t - off] : 0;
    __syncthreads();
    s[t] += v;
    __syncthreads();
  }
  if (t < nb) bsum[t] = (t == 0) ? 0 : s[t-1];   // exclusive
}

__global__ void k_bput(const int* __restrict__ cnt, const int* __restrict__ bsum,
                       int* __restrict__ rp, int n){
  __shared__ int s[256];
  int b = blockIdx.x, t = threadIdx.x;
  int i = b*256 + t;
  int v = (i < n) ? cnt[i] : 0;
  s[t] = v;
  __syncthreads();
  for (int off = 1; off < 256; off <<= 1){
    int u = (t >= off) ? s[t - off] : 0;
    __syncthreads();
    s[t] += u;
    __syncthreads();
  }
  int incl = s[t];
  if (i < n)  rp[i] = bsum[b] + incl - v;
  if (i == n-1) rp[n] = bsum[b] + incl;          // total = E
}

// packed edge record: .x = src index, .y = norm (float bits). ONE 8B scatter.
__global__ void k_fill(const int* __restrict__ src, const int* __restrict__ dst, int E,
                       const int* __restrict__ rp, int* __restrict__ cur,
                       const float* __restrict__ dinv,
                       int2* __restrict__ ef){
  int i = blockIdx.x*blockDim.x + threadIdx.x;
  if (i < E){
    int d = dst[i], s = src[i];
    int pos = rp[d] + atomicAdd(&cur[d], 1);
    int2 rec; rec.x = s; rec.y = __float_as_int(dinv[s] * dinv[d]);
    ef[pos] = rec;
  }
}

// ---------------- fused layer 1: h1 = relu( (A x_t) W1 + b1 ) ---------------
// Wave per node; half-waves split even/odd edges; 8 edges per half per iter
// -> 16 gathers in flight per wave.
__launch_bounds__(256)
__global__ void k_l1(const float* __restrict__ xt, const int* __restrict__ rp,
                     const int2* __restrict__ ef, const float* __restrict__ invd,
                     const float* __restrict__ W1, const float* __restrict__ b1,
                     float* __restrict__ h1){
  __shared__ float sh[4][2][32];
  int wv = threadIdx.x >> 6, lane = threadIdx.x & 63;
  int n = blockIdx.x*4 + wv;
  if (n >= NN) return;
  int half = lane >> 5, f = lane & 31;

  float acc0 = half ? 0.f : invd[n] * xt[(size_t)n*FF + f];
  float acc1 = 0.f;
  int e = rp[n] + half, e1 = rp[n+1];
  for (; e + 14 < e1; e += 16){               // 8 edges per half per iter
    int2 p0 = ef[e   ], p1 = ef[e+ 2], p2 = ef[e+ 4], p3 = ef[e+ 6];
    int2 p4 = ef[e+ 8], p5 = ef[e+10], p6 = ef[e+12], p7 = ef[e+14];
    float v0 = xt[(size_t)p0.x*FF + f];
    float v1 = xt[(size_t)p1.x*FF + f];
    float v2 = xt[(size_t)p2.x*FF + f];
    float v3 = xt[(size_t)p3.x*FF + f];
    float v4 = xt[(size_t)p4.x*FF + f];
    float v5 = xt[(size_t)p5.x*FF + f];
    float v6 = xt[(size_t)p6.x*FF + f];
    float v7 = xt[(size_t)p7.x*FF + f];
    acc0 = fmaf(__int_as_float(p0.y), v0, acc0);
    acc1 = fmaf(__int_as_float(p1.y), v1, acc1);
    acc0 = fmaf(__int_as_float(p2.y), v2, acc0);
    acc1 = fmaf(__int_as_float(p3.y), v3, acc1);
    acc0 = fmaf(__int_as_float(p4.y), v4, acc0);
    acc1 = fmaf(__int_as_float(p5.y), v5, acc1);
    acc0 = fmaf(__int_as_float(p6.y), v6, acc0);
    acc1 = fmaf(__int_as_float(p7.y), v7, acc1);
  }
  for (; e + 6 < e1; e += 8){                 // 4 edges per half
    int2 p0 = ef[e], p1 = ef[e+2], p2 = ef[e+4], p3 = ef[e+6];
    float v0 = xt[(size_t)p0.x*FF + f];
    float v1 = xt[(size_t)p1.x*FF + f];
    float v2 = xt[(size_t)p2.x*FF + f];
    float v3 = xt[(size_t)p3.x*FF + f];
    acc0 = fmaf(__int_as_float(p0.y), v0, acc0);
    acc1 = fmaf(__int_as_float(p1.y), v1, acc1);
    acc0 = fmaf(__int_as_float(p2.y), v2, acc0);
    acc1 = fmaf(__int_as_float(p3.y), v3, acc1);
  }
  for (; e < e1; e += 2){
    int2 p = ef[e];
    acc0 = fmaf(__int_as_float(p.y), xt[(size_t)p.x*FF + f], acc0);
  }
  float acc = acc0 + acc1;
  sh[wv][half][f] = acc;                 // intra-wave LDS (lockstep)
  if (lane < 32) sh[wv][0][f] = acc + sh[wv][1][f];
  float hj = b1[lane];
  const float4* row = (const float4*)&sh[wv][0][0];
  #pragma unroll
  for (int i4 = 0; i4 < 8; ++i4){
    float4 v = row[i4];                  // same-addr broadcast
    hj = fmaf(v.x, W1[(4*i4  )*HH + lane], hj);
    hj = fmaf(v.y, W1[(4*i4+1)*HH + lane], hj);
    hj = fmaf(v.z, W1[(4*i4+2)*HH + lane], hj);
    hj = fmaf(v.w, W1[(4*i4+3)*HH + lane], hj);
  }
  h1[(size_t)n*HH + lane] = fmaxf(hj, 0.f);
}

// ---------------- fused layer 2: h2 = relu( (A h1) W2 + b2 ) ----------------
// Wave per node; lane = feature; 16 edges/iter, 4 accumulators
// -> 16 gathers in flight per wave.
__launch_bounds__(256)
__global__ void k_l2(const float* __restrict__ h1, const int* __restrict__ rp,
                     const int2* __restrict__ ef, const float* __restrict__ invd,
                     const float* __restrict__ W2, const float* __restrict__ b2,
                     float* __restrict__ h2){
  __shared__ float sh[4][64];
  int wv = threadIdx.x >> 6, lane = threadIdx.x & 63;
  int n = blockIdx.x*4 + wv;
  if (n >= NN) return;

  float acc0 = invd[n] * h1[(size_t)n*HH + lane];
  float acc1 = 0.f, acc2a = 0.f, acc3a = 0.f;
  int e = rp[n], e1 = rp[n+1];
  for (; e + 16 <= e1; e += 16){
    int2 p0 = ef[e   ], p1 = ef[e+ 1], p2 = ef[e+ 2], p3 = ef[e+ 3];
    int2 p4 = ef[e+ 4], p5 = ef[e+ 5], p6 = ef[e+ 6], p7 = ef[e+ 7];
    int2 p8 = ef[e+ 8], p9 = ef[e+ 9], pa = ef[e+10], pb = ef[e+11];
    int2 pc = ef[e+12], pd = ef[e+13], pe = ef[e+14], pf = ef[e+15];
    float v0 = h1[(size_t)p0.x*HH + lane];
    float v1 = h1[(size_t)p1.x*HH + lane];
    float v2 = h1[(size_t)p2.x*HH + lane];
    float v3 = h1[(size_t)p3.x*HH + lane];
    float v4 = h1[(size_t)p4.x*HH + lane];
    float v5 = h1[(size_t)p5.x*HH + lane];
    float v6 = h1[(size_t)p6.x*HH + lane];
    float v7 = h1[(size_t)p7.x*HH + lane];
    float v8 = h1[(size_t)p8.x*HH + lane];
    float v9 = h1[(size_t)p9.x*HH + lane];
    float va = h1[(size_t)pa.x*HH + lane];
    float vb = h1[(size_t)pb.x*HH + lane];
    float vc = h1[(size_t)pc.x*HH + lane];
    float vd = h1[(size_t)pd.x*HH + lane];
    float ve = h1[(size_t)pe.x*HH + lane];
    float vf = h1[(size_t)pf.x*HH + lane];
    acc0  = fmaf(__int_as_float(p0.y), v0, acc0);
    acc1  = fmaf(__int_as_float(p1.y), v1, acc1);
    acc2a = fmaf(__int_as_float(p2.y), v2, acc2a);
    acc3a = fmaf(__int_as_float(p3.y), v3, acc3a);
    acc0  = fmaf(__int_as_float(p4.y), v4, acc0);
    acc1  = fmaf(__int_as_float(p5.y), v5, acc1);
    acc2a = fmaf(__int_as_float(p6.y), v6, acc2a);
    acc3a = fmaf(__int_as_float(p7.y), v7, acc3a);
    acc0  = fmaf(__int_as_float(p8.y), v8, acc0);
    acc1  = fmaf(__int_as_float(p9.y), v9, acc1);
    acc2a = fmaf(__int_as_float(pa.y), va, acc2a);
    acc3a = fmaf(__int_as_float(pb.y), vb, acc3a);
    acc0  = fmaf(__int_as_float(pc.y), vc, acc0);
    acc1  = fmaf(__int_as_float(pd.y), vd, acc1);
    acc2a = fmaf(__int_as_float(pe.y), ve, acc2a);
    acc3a = fmaf(__int_as_float(pf.y), vf, acc3a);
  }
  for (; e + 8 <= e1; e += 8){
    int2 p0 = ef[e  ], p1 = ef[e+1], p2 = ef[e+2], p3 = ef[e+3];
    int2 p4 = ef[e+4], p5 = ef[e+5], p6 = ef[e+6], p7 = ef[e+7];
    float v0 = h1[(size_t)p0.x*HH + lane];
    float v1 = h1[(size_t)p1.x*HH + lane];
    float v2 = h1[(size_t)p2.x*HH + lane];
    float v3 = h1[(size_t)p3.x*HH + lane];
    float v4 = h1[(size_t)p4.x*HH + lane];
    float v5 = h1[(size_t)p5.x*HH + lane];
    float v6 = h1[(size_t)p6.x*HH + lane];
    float v7 = h1[(size_t)p7.x*HH + lane];
    acc0  = fmaf(__int_as_float(p0.y), v0, acc0);
    acc1  = fmaf(__int_as_float(p1.y), v1, acc1);
    acc2a = fmaf(__int_as_float(p2.y), v2, acc2a);
    acc3a = fmaf(__int_as_float(p3.y), v3, acc3a);
    acc0  = fmaf(__int_as_float(p4.y), v4, acc0);
    acc1  = fmaf(__int_as_float(p5.y), v5, acc1);
    acc2a = fmaf(__int_as_float(p6.y), v6, acc2a);
    acc3a = fmaf(__int_as_float(p7.y), v7, acc3a);
  }
  for (; e < e1; ++e){
    int2 p = ef[e];
    acc0 = fmaf(__int_as_float(p.y), h1[(size_t)p.x*HH + lane], acc0);
  }
  sh[wv][lane] = (acc0 + acc1) + (acc2a + acc3a);   // intra-wave LDS
  float hj = b2[lane];
  const float4* row = (const float4*)&sh[wv][0];
  #pragma unroll
  for (int i4 = 0; i4 < 16; ++i4){
    float4 v = row[i4];
    hj = fmaf(v.x, W2[(4*i4  )*HH + lane], hj);
    hj = fmaf(v.y, W2[(4*i4+1)*HH + lane], hj);
    hj = fmaf(v.z, W2[(4*i4+2)*HH + lane], hj);
    hj = fmaf(v.w, W2[(4*i4+3)*HH + lane], hj);
  }
  h2[(size_t)n*HH + lane] = fmaxf(hj, 0.f);
}

// ---------------- fused GRU step, v4: one 16-node tile per block -------------
#define GRB 16
__launch_bounds__(384)
__global__ void k_gruf(const float* __restrict__ h2, const float* __restrict__ hprev,
                       const float* __restrict__ Wih, const float* __restrict__ Whh,
                       const float* __restrict__ bih, const float* __restrict__ bhh,
                       float* __restrict__ hnew){
  __shared__ float sh[2][GRB][64];   // [0]=h2 rows, [1]=hprev rows (8 KB)
  __shared__ float ex[6][GRB][64];   // gate exchange (24 KB)
  int tid = threadIdx.x, wv = tid >> 6, lane = tid & 63;
  int side = wv / 3;
  int gate = wv - side*3;
  int n0 = blockIdx.x * GRB;

  // stage h tile FIRST (deepest in vmcnt queue), then weights
  for (int i = tid; i < 2*GRB*16; i += 384){
    if (i < GRB*16) ((float4*)sh)[i] = ((const float4*)(h2    + (size_t)n0*64))[i];
    else            ((float4*)sh)[i] = ((const float4*)(hprev + (size_t)n0*64))[i - GRB*16];
  }
  const float* Wsel = side ? Whh : Wih;
  float bg = (side ? bhh : bih)[gate*64 + lane];
  float w[64];
  {
    const float* wr = Wsel + (size_t)(gate*64 + lane)*64;
    #pragma unroll
    for (int k = 0; k < 64; k += 4){
      float4 v = *(const float4*)(wr + k);
      w[k]=v.x; w[k+1]=v.y; w[k+2]=v.z; w[k+3]=v.w;
    }
  }
  __syncthreads();

  float a[GRB];
  #pragma unroll
  for (int r0 = 0; r0 < GRB; r0 += 4){
    const float* h0 = &sh[side][r0    ][0];
    const float* h1p= &sh[side][r0 + 1][0];
    const float* h2p= &sh[side][r0 + 2][0];
    const float* h3 = &sh[side][r0 + 3][0];
    float s0=0.f, s1=0.f, s2=0.f, s3=0.f;
    #pragma unroll
    for (int k = 0; k < 64; k += 4){
      float4 v0 = *(const float4*)(h0 + k);    // LDS same-addr broadcast
      float4 v1 = *(const float4*)(h1p + k);
      float4 v2 = *(const float4*)(h2p + k);
      float4 v3 = *(const float4*)(h3 + k);
      s0 = fmaf(v0.x, w[k], s0); s0 = fmaf(v0.y, w[k+1], s0);
      s0 = fmaf(v0.z, w[k+2], s0); s0 = fmaf(v0.w, w[k+3], s0);
      s1 = fmaf(v1.x, w[k], s1); s1 = fmaf(v1.y, w[k+1], s1);
      s1 = fmaf(v1.z, w[k+2], s1); s1 = fmaf(v1.w, w[k+3], s1);
      s2 = fmaf(v2.x, w[k], s2); s2 = fmaf(v2.y, w[k+1], s2);
      s2 = fmaf(v2.z, w[k+2], s2); s2 = fmaf(v2.w, w[k+3], s2);
      s3 = fmaf(v3.x, w[k], s3); s3 = fmaf(v3.y, w[k+1], s3);
      s3 = fmaf(v3.z, w[k+2], s3); s3 = fmaf(v3.w, w[k+3], s3);
    }
    a[r0]=s0; a[r0+1]=s1; a[r0+2]=s2; a[r0+3]=s3;
  }
  #pragma unroll
  for (int r = 0; r < GRB; ++r) ex[wv][r][lane] = a[r] + bg;
  __syncthreads();
  for (int i = tid; i < GRB*64; i += 384){
    int row = i >> 6, col = i & 63;
    float ir = ex[0][row][col], iz = ex[1][row][col], in_ = ex[2][row][col];
    float hr = ex[3][row][col], hz = ex[4][row][col], hn  = ex[5][row][col];
    float rg = 1.f/(1.f + expf(-(ir + hr)));
    float zg = 1.f/(1.f + expf(-(iz + hz)));
    float nv = tanhf(in_ + rg*hn);
    float hp = sh[1][row][col];
    hnew[(size_t)(n0 + row)*64 + col] = (1.f - zg)*nv + zg*hp;
  }
}

// ---------------- head: logits = relu(h@Wc1+bc1)@Wc2 + bc2 ----------------
__global__ void k_head(const float* __restrict__ h, const float* __restrict__ Wc1,
                       const float* __restrict__ bc1, const float* __restrict__ Wc2,
                       const float* __restrict__ bc2, float* __restrict__ out){
  __shared__ float w1[64*32];
  __shared__ float w2[32];
  for (int i = threadIdx.x; i < 64*32; i += blockDim.x) w1[i] = Wc1[i];
  if (threadIdx.x < 32) w2[threadIdx.x] = Wc2[threadIdx.x];
  __syncthreads();
  int n = blockIdx.x*blockDim.x + threadIdx.x;
  if (n >= NN) return;
  const float* hr = h + (size_t)n*64;
  float hreg[64];
  #pragma unroll
  for (int k = 0; k < 64; ++k) hreg[k] = hr[k];
  float acc2 = bc2[0];
  #pragma unroll
  for (int c = 0; c < 32; ++c){
    float a = bc1[c];
    #pragma unroll
    for (int k = 0; k < 64; ++k) a = fmaf(hreg[k], w1[k*32 + c], a);
    a = fmaxf(a, 0.f);
    acc2 = fmaf(a, w2[c], acc2);
  }
  out[n] = acc2;
}

// ---------------- launch ----------------
extern "C" void kernel_launch(void* const* d_in, const int* in_sizes, int n_in,
                              void* d_out, int out_size, void* d_ws, size_t ws_size,
                              hipStream_t stream){
  const float* x    = (const float*)d_in[0];
  const int*   ei   = (const int*)  d_in[1];
  const float* W1   = (const float*)d_in[2];
  const float* b1   = (const float*)d_in[3];
  const float* W2   = (const float*)d_in[4];
  const float* b2   = (const float*)d_in[5];
  const float* W_ih = (const float*)d_in[6];
  const float* W_hh = (const float*)d_in[7];
  const float* b_ih = (const float*)d_in[8];
  const float* b_hh = (const float*)d_in[9];
  const float* Wc1  = (const float*)d_in[10];
  const float* bc1  = (const float*)d_in[11];
  const float* Wc2  = (const float*)d_in[12];
  const float* bc2  = (const float*)d_in[13];
  int E = in_sizes[1] / 2;
  const int* src = ei;
  const int* dst = ei + E;
  int NB = (NN + 255)/256;   // 196 scan blocks

  char* w = (char*)d_ws;
  auto alloc = [&](size_t bytes){ char* p = w; w += align256(bytes); return p; };
  int*   cnt  = (int*)  alloc((size_t)NN*4);
  int*   rp   = (int*)  alloc((size_t)(NN+1)*4);
  int*   cur  = (int*)  alloc((size_t)NN*4);
  int*   bsum = (int*)  alloc((size_t)NB*4);
  float* dinv = (float*)alloc((size_t)NN*4);
  float* invd = (float*)alloc((size_t)NN*4);
  int2*  ef   = (int2*) alloc((size_t)E*8);
  float* h1   = (float*)alloc((size_t)NN*HH*4);
  float* h2   = (float*)alloc((size_t)NN*HH*4);
  float* hA   = (float*)alloc((size_t)NN*HH*4);
  float* hB   = (float*)alloc((size_t)NN*HH*4);
  if ((size_t)(w - (char*)d_ws) > ws_size) return;   // clean diagnostic fail

  hipMemsetAsync(cnt, 0, (size_t)NN*4, stream);
  hipMemsetAsync(cur, 0, (size_t)NN*4, stream);
  hipMemsetAsync(hA,  0, (size_t)NN*HH*4, stream);   // h0 = 0

  k_count<<<(E+255)/256, 256, 0, stream>>>(dst, E, cnt);
  k_dinv <<<(NN+255)/256, 256, 0, stream>>>(cnt, dinv, invd, NN);
  k_bsum <<<NB, 256, 0, stream>>>(cnt, bsum, NN);
  k_bscan<<<1, 256, 0, stream>>>(bsum, NB);
  k_bput <<<NB, 256, 0, stream>>>(cnt, bsum, rp, NN);
  k_fill <<<(E+255)/256, 256, 0, stream>>>(src, dst, E, rp, cur, dinv, ef);

  float* hprev = hA;
  float* hnext = hB;
  for (int t = 0; t < TT; ++t){
    const float* xt = x + (size_t)t*NN*FF;
    k_l1<<<(NN + 3)/4, 256, 0, stream>>>(xt, rp, ef, invd, W1, b1, h1);
    k_l2<<<(NN + 3)/4, 256, 0, stream>>>(h1, rp, ef, invd, W2, b2, h2);
    k_gruf<<<NN/GRB, 384, 0, stream>>>(h2, hprev, W_ih, W_hh, b_ih, b_hh, hnext);
    float* tmp = hprev; hprev = hnext; hnext = tmp;
  }

  // after 12 swaps hprev == hA
  k_head<<<(NN + 255)/256, 256, 0, stream>>>(hprev, Wc1, bc1, Wc2, bc2, (float*)d_out);
}